// Round 2
// baseline (856.703 us; speedup 1.0000x reference)
//
#include <hip/hip_runtime.h>
#include <math.h>

#define N_NODES 100000
#define N_EDGES 1600000
#define NEG_SLOPE 0.2f

// ---- monotone float<->uint mapping for atomicMax on signed floats ----
__device__ __forceinline__ unsigned fmap(float f) {
    unsigned u = __float_as_uint(f);
    return (u & 0x80000000u) ? ~u : (u | 0x80000000u);
}
__device__ __forceinline__ float funmap(unsigned u) {
    return __uint_as_float((u & 0x80000000u) ? (u & 0x7fffffffu) : ~u);
}
#define EMAX_NEG_INF 0x007fffffu   // fmap(-inf)

// ============================================================================
// k1: per-node projection feat = x @ W, attention logits el/er, and init of
//     all accumulators (out=0, emax=-inf, denom=0).  One wave per node.
// ============================================================================
__global__ __launch_bounds__(256) void k1_project(
        const float* __restrict__ x, const float* __restrict__ W,
        const float* __restrict__ attn_l, const float* __restrict__ attn_r,
        float* __restrict__ feat, float* __restrict__ el, float* __restrict__ er,
        unsigned* __restrict__ emax, float* __restrict__ denom,
        float* __restrict__ out) {
    __shared__ float Ws[64 * 64];
    int t = threadIdx.x;
    for (int i = t; i < 1024; i += 256)                 // stage W (16 KB) via float4
        ((float4*)Ws)[i] = ((const float4*)W)[i];
    __syncthreads();

    int lane = t & 63;
    int wib  = t >> 6;                                  // wave in block, 0..3
    int h    = lane >> 4;
    float al = attn_l[lane];                            // attn_l is flat [4*16]
    float ar = attn_r[lane];
    int wavesTotal = (gridDim.x * blockDim.x) >> 6;

    for (int n = blockIdx.x * 4 + wib; n < N_NODES; n += wavesTotal) {
        float xv  = x[n * 64 + lane];
        float acc = 0.f;
        #pragma unroll
        for (int k = 0; k < 64; ++k) {
            float xk = __shfl(xv, k, 64);               // broadcast x[n][k]
            acc = fmaf(xk, Ws[k * 64 + lane], acc);
        }
        feat[n * 64 + lane] = acc;
        out[n * 64 + lane]  = 0.f;                      // init accumulator
        float vl = acc * al, vr = acc * ar;
        #pragma unroll
        for (int off = 8; off >= 1; off >>= 1) {        // reduce within 16-lane head group
            vl += __shfl_xor(vl, off, 64);
            vr += __shfl_xor(vr, off, 64);
        }
        if ((lane & 15) == 0) {
            el[n * 4 + h]    = vl;
            er[n * 4 + h]    = vr;
            emax[n * 4 + h]  = EMAX_NEG_INF;
            denom[n * 4 + h] = 0.f;
        }
    }
}

// ============================================================================
// k2: per-edge raw score + segment max via mapped-uint atomicMax.
//     One thread per edge, 4 heads via float4.
// ============================================================================
__global__ __launch_bounds__(256) void k2_max(
        const int* __restrict__ src, const int* __restrict__ dst,
        const float* __restrict__ el, const float* __restrict__ er,
        unsigned* __restrict__ emax) {
    int e = blockIdx.x * blockDim.x + threadIdx.x;
    if (e >= N_EDGES) return;
    int s = src[e], d = dst[e];
    float4 a = ((const float4*)el)[s];
    float4 b = ((const float4*)er)[d];
    float v;
    v = a.x + b.x; v = v > 0.f ? v : NEG_SLOPE * v; atomicMax(&emax[d * 4 + 0], fmap(v));
    v = a.y + b.y; v = v > 0.f ? v : NEG_SLOPE * v; atomicMax(&emax[d * 4 + 1], fmap(v));
    v = a.z + b.z; v = v > 0.f ? v : NEG_SLOPE * v; atomicMax(&emax[d * 4 + 2], fmap(v));
    v = a.w + b.w; v = v > 0.f ? v : NEG_SLOPE * v; atomicMax(&emax[d * 4 + 3], fmap(v));
}

// ============================================================================
// k3: per-edge exp + unnormalized scatter-aggregate.
//     One wave per edge: lane f handles feature f (head h = f>>4).
//     out[dst] += feat[src] * ex   (normalization deferred to k4)
//     denom[dst][h] += ex
// ============================================================================
__global__ __launch_bounds__(256) void k3_scatter(
        const int* __restrict__ src, const int* __restrict__ dst,
        const float* __restrict__ el, const float* __restrict__ er,
        const unsigned* __restrict__ emax, const float* __restrict__ feat,
        float* __restrict__ out, float* __restrict__ denom) {
    int lane = threadIdx.x & 63;
    int h    = lane >> 4;
    int wave = (blockIdx.x * blockDim.x + threadIdx.x) >> 6;
    int nwav = (gridDim.x * blockDim.x) >> 6;
    for (int e = wave; e < N_EDGES; e += nwav) {
        int s = src[e], d = dst[e];
        float v = el[s * 4 + h] + er[d * 4 + h];        // 16 lanes share addr -> broadcast
        v = v > 0.f ? v : NEG_SLOPE * v;
        float m  = funmap(emax[d * 4 + h]);
        float ex = expf(v - m);
        float fa = feat[s * 64 + lane];                 // coalesced 256B gather
        atomicAdd(&out[d * 64 + lane], fa * ex);        // 4 contiguous lines
        if ((lane & 15) == 0) atomicAdd(&denom[d * 4 + h], ex);
    }
}

// ============================================================================
// k4: per-node epilogue  out = out/denom + bias   (zero in-degree -> bias)
// ============================================================================
__global__ __launch_bounds__(256) void k4_final(
        float* __restrict__ out, const float* __restrict__ denom,
        const float* __restrict__ bias) {
    int i = blockIdx.x * blockDim.x + threadIdx.x;
    if (i >= N_NODES * 64) return;
    int n = i >> 6;
    int h = (i >> 4) & 3;
    float dn  = denom[n * 4 + h];
    float acc = out[i];
    out[i] = (dn > 0.f ? acc / dn : 0.f) + bias[i & 63];
}

// ============================================================================
extern "C" void kernel_launch(void* const* d_in, const int* in_sizes, int n_in,
                              void* d_out, int out_size, void* d_ws, size_t ws_size,
                              hipStream_t stream) {
    const float* x      = (const float*)d_in[0];
    const float* W      = (const float*)d_in[1];
    const float* attn_l = (const float*)d_in[2];
    const float* attn_r = (const float*)d_in[3];
    const float* bias   = (const float*)d_in[4];
    const int*   src    = (const int*)d_in[5];
    const int*   dst    = (const int*)d_in[6];
    float* out = (float*)d_out;

    // workspace layout (all 16B aligned)
    float*    feat  = (float*)d_ws;                       // N*64 f32 = 25.6 MB
    float*    el    = feat + (size_t)N_NODES * 64;        // N*4
    float*    er    = el   + (size_t)N_NODES * 4;         // N*4
    unsigned* emax  = (unsigned*)(er + (size_t)N_NODES * 4);
    float*    denom = (float*)(emax + (size_t)N_NODES * 4);

    k1_project<<<4096, 256, 0, stream>>>(x, W, attn_l, attn_r, feat, el, er, emax, denom, out);
    k2_max<<<(N_EDGES + 255) / 256, 256, 0, stream>>>(src, dst, el, er, emax);
    k3_scatter<<<4096, 256, 0, stream>>>(src, dst, el, er, emax, feat, out, denom);
    k4_final<<<(N_NODES * 64 + 255) / 256, 256, 0, stream>>>(out, denom, bias);
}

// Round 7
// 488.584 us; speedup vs baseline: 1.7534x; 1.7534x over previous
//
#include <hip/hip_runtime.h>
#include <math.h>

#define N_NODES 100000
#define N_EDGES 1600000
#define NEG_SLOPE 0.2f

// ============================================================================
// k1: per-node projection feat = x @ W, attention logits el/er; zero the
//     degree counters and the global segment cursor.  One wave per node.
// ============================================================================
__global__ __launch_bounds__(256) void k1_project(
        const float* __restrict__ x, const float* __restrict__ W,
        const float* __restrict__ attn_l, const float* __restrict__ attn_r,
        float* __restrict__ feat, float* __restrict__ el, float* __restrict__ er,
        int* __restrict__ cursor, int* __restrict__ gtotal) {
    __shared__ float Ws[64 * 64];
    int t = threadIdx.x;
    for (int i = t; i < 1024; i += 256)                 // stage W (16 KB) via float4
        ((float4*)Ws)[i] = ((const float4*)W)[i];
    if (blockIdx.x == 0 && t == 0) *gtotal = 0;
    __syncthreads();

    int lane = t & 63;
    int wib  = t >> 6;                                  // wave in block, 0..3
    int h    = lane >> 4;
    float al = attn_l[lane];                            // attn_l is flat [4*16]
    float ar = attn_r[lane];
    int wavesTotal = (gridDim.x * blockDim.x) >> 6;

    for (int n = blockIdx.x * 4 + wib; n < N_NODES; n += wavesTotal) {
        float xv  = x[n * 64 + lane];
        float acc = 0.f;
        #pragma unroll
        for (int k = 0; k < 64; ++k) {
            float xk = __shfl(xv, k, 64);               // broadcast x[n][k]
            acc = fmaf(xk, Ws[k * 64 + lane], acc);
        }
        feat[n * 64 + lane] = acc;
        float vl = acc * al, vr = acc * ar;
        #pragma unroll
        for (int off = 8; off >= 1; off >>= 1) {        // reduce within 16-lane head group
            vl += __shfl_xor(vl, off, 64);
            vr += __shfl_xor(vr, off, 64);
        }
        if ((lane & 15) == 0) {
            el[n * 4 + h] = vl;
            er[n * 4 + h] = vr;
        }
        if (lane == 0) cursor[n] = 0;                   // zero degree counter
    }
}

// ============================================================================
// k2: degree histogram — cursor[d] = in-degree(d)
// ============================================================================
__global__ __launch_bounds__(256) void k2_hist(
        const int* __restrict__ dst, int* __restrict__ cursor) {
    int e = blockIdx.x * blockDim.x + threadIdx.x;
    if (e < N_EDGES) atomicAdd(&cursor[dst[e]], 1);
}

// ============================================================================
// k3: assign each node a contiguous segment [start, start+deg).
//     Segment ORDER across nodes is irrelevant, so no full prefix scan:
//     wave-local prefix via shfl + ONE global atomicAdd per wave.
//     rowptr[n] = start; cursor[n] = start (becomes fill cursor).
// ============================================================================
__global__ __launch_bounds__(256) void k3_segbase(
        int* __restrict__ cursor, int* __restrict__ rowptr, int* __restrict__ gtotal) {
    int tid  = blockIdx.x * blockDim.x + threadIdx.x;
    int lane = threadIdx.x & 63;
    int n    = tid;
    int deg  = (n < N_NODES) ? cursor[n] : 0;
    // inclusive wave prefix sum
    int incl = deg;
    #pragma unroll
    for (int off = 1; off < 64; off <<= 1) {
        int v = __shfl_up(incl, off, 64);
        if (lane >= off) incl += v;
    }
    int waveTotal = __shfl(incl, 63, 64);
    int base = 0;
    if (lane == 63) base = atomicAdd(gtotal, waveTotal);
    base = __shfl(base, 63, 64);
    int start = base + incl - deg;                      // exclusive prefix
    if (n < N_NODES) {
        rowptr[n] = start;
        cursor[n] = start;
    }
}

// ============================================================================
// k4: fill — edge_src[pos] = src, pos = cursor[dst]++
// ============================================================================
__global__ __launch_bounds__(256) void k4_fill(
        const int* __restrict__ src, const int* __restrict__ dst,
        int* __restrict__ cursor, int* __restrict__ edge_src) {
    int e = blockIdx.x * blockDim.x + threadIdx.x;
    if (e >= N_EDGES) return;
    int pos = atomicAdd(&cursor[dst[e]], 1);
    edge_src[pos] = src[e];
}

// ============================================================================
// k5: gather-aggregate with online softmax.  One wave per dst node.
//     Lane f owns feature f (head h = f>>4).  After k4, cursor[n] == segment
//     end.  No atomics anywhere; epilogue (divide + bias) fused.
// ============================================================================
__global__ __launch_bounds__(256) void k5_gather(
        const int* __restrict__ rowptr, const int* __restrict__ cursor,
        const int* __restrict__ edge_src,
        const float* __restrict__ el, const float* __restrict__ er,
        const float* __restrict__ feat, const float* __restrict__ bias,
        float* __restrict__ out) {
    int lane = threadIdx.x & 63;
    int h    = lane >> 4;
    int n    = (blockIdx.x * blockDim.x + threadIdx.x) >> 6;   // wave id == node
    if (n >= N_NODES) return;

    int   row0 = rowptr[n];                              // broadcast loads
    int   row1 = cursor[n];
    float er_h = er[n * 4 + h];
    float bv   = bias[lane];

    float m = -INFINITY, denom = 0.f, acc = 0.f;
    for (int base = row0; base < row1; base += 64) {
        int nchunk = min(64, row1 - base);
        int sv = (base + lane < row1) ? edge_src[base + lane] : 0;  // coalesced
        for (int j = 0; j < nchunk; ++j) {
            int   s  = __shfl(sv, j, 64);
            float v  = el[s * 4 + h] + er_h;             // 16-lane broadcast load
            v = v > 0.f ? v : NEG_SLOPE * v;             // leaky relu
            float fa = feat[s * 64 + lane];              // coalesced 256B gather
            // online softmax update
            float mn    = fmaxf(m, v);
            float scale = __expf(m - mn);                // first edge: exp(-inf)=0
            float p     = __expf(v - mn);
            acc   = acc * scale + p * fa;
            denom = denom * scale + p;
            m = mn;
        }
    }
    out[n * 64 + lane] = (denom > 0.f ? acc / denom : 0.f) + bv;
}

// ============================================================================
extern "C" void kernel_launch(void* const* d_in, const int* in_sizes, int n_in,
                              void* d_out, int out_size, void* d_ws, size_t ws_size,
                              hipStream_t stream) {
    const float* x      = (const float*)d_in[0];
    const float* W      = (const float*)d_in[1];
    const float* attn_l = (const float*)d_in[2];
    const float* attn_r = (const float*)d_in[3];
    const float* bias   = (const float*)d_in[4];
    const int*   src    = (const int*)d_in[5];
    const int*   dst    = (const int*)d_in[6];
    float* out = (float*)d_out;

    // workspace layout (all 4B types, 16B-aligned ordering)
    float* feat     = (float*)d_ws;                          // N*64 f32 = 25.6 MB
    float* el       = feat + (size_t)N_NODES * 64;           // N*4
    float* er       = el   + (size_t)N_NODES * 4;            // N*4
    int*   cursor   = (int*)(er + (size_t)N_NODES * 4);      // N   (deg -> start -> end)
    int*   rowptr   = cursor + N_NODES;                      // N
    int*   edge_src = rowptr + N_NODES;                      // E = 6.4 MB
    int*   gtotal   = edge_src + N_EDGES;                    // 1

    k1_project<<<4096, 256, 0, stream>>>(x, W, attn_l, attn_r, feat, el, er, cursor, gtotal);
    k2_hist   <<<(N_EDGES + 255) / 256, 256, 0, stream>>>(dst, cursor);
    k3_segbase<<<(N_NODES + 255) / 256, 256, 0, stream>>>(cursor, rowptr, gtotal);
    k4_fill   <<<(N_EDGES + 255) / 256, 256, 0, stream>>>(src, dst, cursor, edge_src);
    k5_gather <<<(N_NODES * 64 + 255) / 256, 256, 0, stream>>>(rowptr, cursor, edge_src,
                                                               el, er, feat, bias, out);
}